// Round 2
// baseline (146.591 us; speedup 1.0000x reference)
//
#include <hip/hip_runtime.h>
#include <hip/hip_bf16.h>

// SingleAttention: q/k/v = X@W+b (fp32 in), out = softmax(q k^T/16) v, fp32 out.
// B=8 S=2048 D_IN=512 D_K=D_V=256.
// ws usage: EXACTLY 16 MB  = ks bf16 [8][2048][256] (8MB) + vt bf16 [8][256][2048] (8MB).

typedef __attribute__((ext_vector_type(4))) float f32x4;
typedef __attribute__((ext_vector_type(8))) short s16x8;
typedef __attribute__((ext_vector_type(4))) short s16x4;

static __device__ __forceinline__ short f2bf(float x) {
  __hip_bfloat16 h = __float2bfloat16(x);
  return *reinterpret_cast<short*>(&h);
}

// K/V projection: P[16384,256] = X @ W + b -> bf16.
// z=0 -> ks row-major [b][s][dk]; z=1 -> vt transposed [b][dv][s].
__global__ __launch_bounds__(256) void proj_kv(
    const float* __restrict__ k_in, const float* __restrict__ v_in,
    const float* __restrict__ bk, const float* __restrict__ bv,
    const float* __restrict__ Wk, const float* __restrict__ Wv,
    short* __restrict__ ks, short* __restrict__ vt) {
  const int z = blockIdx.z;
  const float* X = z == 0 ? k_in : v_in;
  const float* W = z == 0 ? Wk : Wv;
  const float* bias = z == 0 ? bk : bv;
  const int n0 = blockIdx.x * 128;
  const int m0 = blockIdx.y * 128;

  __shared__ short As[128][40];  // [m][k] bf16, +8 pad
  __shared__ short Bs[128][40];  // [n][k] bf16 (W^T tile), +8 pad

  const int tid = threadIdx.x;
  const int lane = tid & 63;
  const int wid = tid >> 6;
  const int wr = wid >> 1, wc = wid & 1;
  const int g = lane >> 4, c = lane & 15;

  f32x4 acc[4][4];
#pragma unroll
  for (int m = 0; m < 4; m++)
#pragma unroll
    for (int n = 0; n < 4; n++) acc[m][n] = (f32x4)0.0f;

  const int arow = tid >> 1, ahalf = tid & 1;  // A: 128 rows x 32 fp32
  const int bn = tid & 127, bhalf = tid >> 7;  // B: 128 cols x (16 k per half)

  for (int kt = 0; kt < 16; ++kt) {
    const int k0 = kt * 32;
    const float* ap = &X[(m0 + arow) * 512 + k0 + ahalf * 16];
    f32x4 a0 = *(const f32x4*)(ap + 0);
    f32x4 a1 = *(const f32x4*)(ap + 4);
    f32x4 a2 = *(const f32x4*)(ap + 8);
    f32x4 a3 = *(const f32x4*)(ap + 12);
    float wv[16];
#pragma unroll
    for (int j = 0; j < 16; j++)
      wv[j] = W[(k0 + bhalf * 16 + j) * 256 + n0 + bn];  // coalesced per j
    __syncthreads();  // previous iteration's fragment reads done
    s16x8 ac0, ac1, w0, w1;
#pragma unroll
    for (int i = 0; i < 4; i++) {
      ac0[i] = f2bf(a0[i]);
      ac0[i + 4] = f2bf(a1[i]);
      ac1[i] = f2bf(a2[i]);
      ac1[i + 4] = f2bf(a3[i]);
    }
#pragma unroll
    for (int j = 0; j < 8; j++) {
      w0[j] = f2bf(wv[j]);
      w1[j] = f2bf(wv[8 + j]);
    }
    *(s16x8*)&As[arow][ahalf * 16 + 0] = ac0;
    *(s16x8*)&As[arow][ahalf * 16 + 8] = ac1;
    *(s16x8*)&Bs[bn][bhalf * 16 + 0] = w0;
    *(s16x8*)&Bs[bn][bhalf * 16 + 8] = w1;
    __syncthreads();
    s16x8 af[4], bfr[4];
#pragma unroll
    for (int m = 0; m < 4; m++)
      af[m] = *(const s16x8*)&As[wr * 64 + m * 16 + c][g * 8];
#pragma unroll
    for (int n = 0; n < 4; n++)
      bfr[n] = *(const s16x8*)&Bs[wc * 64 + n * 16 + c][g * 8];
#pragma unroll
    for (int m = 0; m < 4; m++)
#pragma unroll
      for (int n = 0; n < 4; n++)
        acc[m][n] = __builtin_amdgcn_mfma_f32_16x16x32_bf16(af[m], bfr[n],
                                                            acc[m][n], 0, 0, 0);
  }

  float bv4[4];
#pragma unroll
  for (int n = 0; n < 4; n++) bv4[n] = bias[n0 + wc * 64 + n * 16 + c];

  if (z == 0) {
#pragma unroll
    for (int m = 0; m < 4; m++) {
      const int row0 = m0 + wr * 64 + m * 16 + g * 4;
#pragma unroll
      for (int n = 0; n < 4; n++) {
        const int col = n0 + wc * 64 + n * 16 + c;
#pragma unroll
        for (int r = 0; r < 4; r++)
          ks[(row0 + r) * 256 + col] = f2bf(acc[m][n][r] + bv4[n]);
      }
    }
  } else {
#pragma unroll
    for (int m = 0; m < 4; m++) {
      const int row0 = m0 + wr * 64 + m * 16 + g * 4;
      const int bb = row0 >> 11, s = row0 & 2047;
#pragma unroll
      for (int n = 0; n < 4; n++) {
        const int col = n0 + wc * 64 + n * 16 + c;
        s16x4 pk;
#pragma unroll
        for (int r = 0; r < 4; r++) pk[r] = f2bf(acc[m][n][r] + bv4[n]);
        *(s16x4*)&vt[bb * 524288 + col * 2048 + s] = pk;  // vt[b][dv][s]
      }
    }
  }
}

// Fused Q-projection + flash attention: grid (32 q-tiles, 8 batches), 4 waves.
__global__ __launch_bounds__(256) void attn_fused(
    const float* __restrict__ q_in, const float* __restrict__ Wq,
    const float* __restrict__ bq, const short* __restrict__ ks,
    const short* __restrict__ vt, float* __restrict__ out) {
  const int b = blockIdx.y;
  const int q0 = blockIdx.x * 64;

  __shared__ short Ks[64][264];    // [kv][d] +8 pad; also Q scratch in phase 0
  __shared__ short Vs[256][72];    // [dv][kv] +8 pad; also W^T scratch in phase 0
  __shared__ short Ps[4][16][72];  // wave-private P, +8 pad

  const int tid = threadIdx.x;
  const int lane = tid & 63;
  const int wid = tid >> 6;
  const int g = lane >> 4, c = lane & 15;

  // ---- Phase 0: Q-tile projection, Q = q_in @ (Wq/16) + bq/16 -> Ks LDS ----
  {
    f32x4 accq[16];
#pragma unroll
    for (int f = 0; f < 16; f++) accq[f] = (f32x4)0.0f;
    const int xrow = tid >> 2, xseg = tid & 3;  // 64 rows x 32 fp32
    for (int kt = 0; kt < 16; ++kt) {
      const int k0 = kt * 32;
      const float* xp = &q_in[((b << 11) + q0 + xrow) * 512 + k0 + xseg * 8];
      f32x4 x0 = *(const f32x4*)xp;
      f32x4 x1 = *(const f32x4*)(xp + 4);
      float wv[32];
#pragma unroll
      for (int j = 0; j < 32; j++)
        wv[j] = Wq[(k0 + j) * 256 + tid] * 0.0625f;  // coalesced per j
      __syncthreads();  // previous iteration's fragment reads done
      s16x8 xc;
#pragma unroll
      for (int i = 0; i < 4; i++) {
        xc[i] = f2bf(x0[i]);
        xc[i + 4] = f2bf(x1[i]);
      }
      *(s16x8*)&Ks[xrow][xseg * 8] = xc;  // Xs tile in Ks[.][0..31]
#pragma unroll
      for (int s = 0; s < 4; s++) {
        s16x8 w8;
#pragma unroll
        for (int j = 0; j < 8; j++) w8[j] = f2bf(wv[s * 8 + j]);
        *(s16x8*)&Vs[tid][s * 8] = w8;  // Wq^T tile in Vs[.][0..31]
      }
      __syncthreads();
      const s16x8 xa = *(const s16x8*)&Ks[wid * 16 + c][g * 8];
#pragma unroll
      for (int f = 0; f < 16; f++) {
        const s16x8 wb = *(const s16x8*)&Vs[f * 16 + c][g * 8];
        accq[f] = __builtin_amdgcn_mfma_f32_16x16x32_bf16(xa, wb, accq[f], 0, 0, 0);
      }
    }
    __syncthreads();  // fragment reads done before Q overwrites Ks
#pragma unroll
    for (int f = 0; f < 16; f++) {
      const float bb = bq[f * 16 + c] * 0.0625f;
#pragma unroll
      for (int r = 0; r < 4; r++)
        Ks[wid * 16 + g * 4 + r][f * 16 + c] = f2bf(accq[f][r] + bb);
    }
    __syncthreads();
  }

  // hoist Q fragments (scaled)
  s16x8 qf[8];
#pragma unroll
  for (int d = 0; d < 8; d++)
    qf[d] = *(const s16x8*)&Ks[wid * 16 + c][d * 32 + g * 8];

  f32x4 o[16];
#pragma unroll
  for (int f = 0; f < 16; f++) o[f] = (f32x4)0.0f;
  float m_r[4] = {-1e30f, -1e30f, -1e30f, -1e30f};
  float l_r[4] = {0.f, 0.f, 0.f, 0.f};

  for (int kt = 0; kt < 32; ++kt) {
    // stage K tile [64][256] and V^T tile [256][64]
    s16x8 kreg[8], vreg[8];
#pragma unroll
    for (int i = 0; i < 8; i++) {
      const int ch = tid + i * 256;
      kreg[i] = *(const s16x8*)&ks[((b << 11) + kt * 64 + (ch >> 5)) * 256 +
                                   (ch & 31) * 8];
      vreg[i] = *(const s16x8*)&vt[b * 524288 + (ch >> 3) * 2048 + kt * 64 +
                                   (ch & 7) * 8];
    }
    __syncthreads();  // previous tile's reads (and phase-0 qf reads) done
#pragma unroll
    for (int i = 0; i < 8; i++) {
      const int ch = tid + i * 256;
      *(s16x8*)&Ks[ch >> 5][(ch & 31) * 8] = kreg[i];
      *(s16x8*)&Vs[ch >> 3][(ch & 7) * 8] = vreg[i];
    }
    __syncthreads();

    // S = Q K^T  (16 q-rows x 64 kv per wave)
    f32x4 sf[4];
#pragma unroll
    for (int nf = 0; nf < 4; nf++) sf[nf] = (f32x4)0.0f;
#pragma unroll
    for (int d = 0; d < 8; d++) {
#pragma unroll
      for (int nf = 0; nf < 4; nf++) {
        const s16x8 kf = *(const s16x8*)&Ks[nf * 16 + c][d * 32 + g * 8];
        sf[nf] = __builtin_amdgcn_mfma_f32_16x16x32_bf16(qf[d], kf, sf[nf], 0, 0, 0);
      }
    }

    // online softmax (row g*4+r spread over 16 lanes of group g)
    float sc[4];
#pragma unroll
    for (int r = 0; r < 4; r++) {
      float mx = fmaxf(fmaxf(sf[0][r], sf[1][r]), fmaxf(sf[2][r], sf[3][r]));
      mx = fmaxf(mx, __shfl_xor(mx, 1, 64));
      mx = fmaxf(mx, __shfl_xor(mx, 2, 64));
      mx = fmaxf(mx, __shfl_xor(mx, 4, 64));
      mx = fmaxf(mx, __shfl_xor(mx, 8, 64));
      const float mn = fmaxf(m_r[r], mx);
      sc[r] = __expf(m_r[r] - mn);
      m_r[r] = mn;
      float sum = 0.f;
#pragma unroll
      for (int nf = 0; nf < 4; nf++) {
        const float p = __expf(sf[nf][r] - mn);
        sf[nf][r] = p;
        sum += p;
      }
      sum += __shfl_xor(sum, 1, 64);
      sum += __shfl_xor(sum, 2, 64);
      sum += __shfl_xor(sum, 4, 64);
      sum += __shfl_xor(sum, 8, 64);
      l_r[r] = l_r[r] * sc[r] + sum;
    }
#pragma unroll
    for (int f = 0; f < 16; f++)
#pragma unroll
      for (int r = 0; r < 4; r++) o[f][r] *= sc[r];

    // P -> LDS (re-fragment for PV A-operand)
#pragma unroll
    for (int nf = 0; nf < 4; nf++)
#pragma unroll
      for (int r = 0; r < 4; r++) Ps[wid][g * 4 + r][nf * 16 + c] = f2bf(sf[nf][r]);
    __syncthreads();

    // O += P V
#pragma unroll
    for (int k2 = 0; k2 < 2; k2++) {
      const s16x8 pa = *(const s16x8*)&Ps[wid][c][k2 * 32 + g * 8];
#pragma unroll
      for (int f = 0; f < 16; f++) {
        const s16x8 vf = *(const s16x8*)&Vs[f * 16 + c][k2 * 32 + g * 8];
        o[f] = __builtin_amdgcn_mfma_f32_16x16x32_bf16(pa, vf, o[f], 0, 0, 0);
      }
    }
  }

#pragma unroll
  for (int f = 0; f < 16; f++) {
#pragma unroll
    for (int r = 0; r < 4; r++) {
      const int row = q0 + wid * 16 + g * 4 + r;
      out[((b << 11) + row) * 256 + f * 16 + c] = o[f][r] / l_r[r];
    }
  }
}

extern "C" void kernel_launch(void* const* d_in, const int* in_sizes, int n_in,
                              void* d_out, int out_size, void* d_ws,
                              size_t ws_size, hipStream_t stream) {
  const float* q_in = (const float*)d_in[0];
  const float* k_in = (const float*)d_in[1];
  const float* v_in = (const float*)d_in[2];
  const float* Wq = (const float*)d_in[3];
  const float* bq = (const float*)d_in[4];
  const float* Wk = (const float*)d_in[5];
  const float* bk = (const float*)d_in[6];
  const float* Wv = (const float*)d_in[7];
  const float* bv = (const float*)d_in[8];
  float* out = (float*)d_out;

  char* ws = (char*)d_ws;
  short* ksb = (short*)ws;                 // 8 MB  [b][s][dk] bf16
  short* vtb = (short*)(ws + (8 << 20));   // 8 MB  [b][dv][s] bf16

  proj_kv<<<dim3(2, 128, 2), dim3(256), 0, stream>>>(k_in, v_in, bk, bv, Wk, Wv,
                                                     ksb, vtb);
  attn_fused<<<dim3(32, 8), dim3(256), 0, stream>>>(q_in, Wq, bq, ksb, vtb, out);
}

// Round 3
// 146.465 us; speedup vs baseline: 1.0009x; 1.0009x over previous
//
#include <hip/hip_runtime.h>
#include <hip/hip_bf16.h>

// SingleAttention: q/k/v = X@W+b (fp32 in), out = softmax(q k^T/16) v, fp32 out.
// B=8 S=2048 D_IN=512 D_K=D_V=256.
// ws usage: EXACTLY 16 MB = ks bf16 [8][2048][256] (8MB) + vt bf16 [8][256][2048] (8MB).

typedef __attribute__((ext_vector_type(4))) float f32x4;
typedef __attribute__((ext_vector_type(8))) short s16x8;
typedef __attribute__((ext_vector_type(4))) short s16x4;

static __device__ __forceinline__ short f2bf(float x) {
  __hip_bfloat16 h = __float2bfloat16(x);
  return *reinterpret_cast<short*>(&h);
}

// K/V projection: P[16384,256] = X @ W + b -> bf16.
// z=0 -> ks row-major [b][s][dk]; z=1 -> vt transposed [b][dv][s].
__global__ __launch_bounds__(256) void proj_kv(
    const float* __restrict__ k_in, const float* __restrict__ v_in,
    const float* __restrict__ bk, const float* __restrict__ bv,
    const float* __restrict__ Wk, const float* __restrict__ Wv,
    short* __restrict__ ks, short* __restrict__ vt) {
  const int z = blockIdx.z;
  const float* X = z == 0 ? k_in : v_in;
  const float* W = z == 0 ? Wk : Wv;
  const float* bias = z == 0 ? bk : bv;
  const int n0 = blockIdx.x * 128;
  const int m0 = blockIdx.y * 128;

  __shared__ short As[128][40];
  __shared__ short Bs[128][40];

  const int tid = threadIdx.x;
  const int lane = tid & 63;
  const int wid = tid >> 6;
  const int wr = wid >> 1, wc = wid & 1;
  const int g = lane >> 4, c = lane & 15;

  f32x4 acc[4][4];
#pragma unroll
  for (int m = 0; m < 4; m++)
#pragma unroll
    for (int n = 0; n < 4; n++) acc[m][n] = (f32x4)0.0f;

  const int arow = tid >> 1, ahalf = tid & 1;
  const int bn = tid & 127, bhalf = tid >> 7;

  for (int kt = 0; kt < 16; ++kt) {
    const int k0 = kt * 32;
    const float* ap = &X[(m0 + arow) * 512 + k0 + ahalf * 16];
    f32x4 a0 = *(const f32x4*)(ap + 0);
    f32x4 a1 = *(const f32x4*)(ap + 4);
    f32x4 a2 = *(const f32x4*)(ap + 8);
    f32x4 a3 = *(const f32x4*)(ap + 12);
    float wv[16];
#pragma unroll
    for (int j = 0; j < 16; j++)
      wv[j] = W[(k0 + bhalf * 16 + j) * 256 + n0 + bn];
    __syncthreads();
    s16x8 ac0, ac1, w0, w1;
#pragma unroll
    for (int i = 0; i < 4; i++) {
      ac0[i] = f2bf(a0[i]);
      ac0[i + 4] = f2bf(a1[i]);
      ac1[i] = f2bf(a2[i]);
      ac1[i + 4] = f2bf(a3[i]);
    }
#pragma unroll
    for (int j = 0; j < 8; j++) {
      w0[j] = f2bf(wv[j]);
      w1[j] = f2bf(wv[8 + j]);
    }
    *(s16x8*)&As[arow][ahalf * 16 + 0] = ac0;
    *(s16x8*)&As[arow][ahalf * 16 + 8] = ac1;
    *(s16x8*)&Bs[bn][bhalf * 16 + 0] = w0;
    *(s16x8*)&Bs[bn][bhalf * 16 + 8] = w1;
    __syncthreads();
    s16x8 af[4], bfr[4];
#pragma unroll
    for (int m = 0; m < 4; m++)
      af[m] = *(const s16x8*)&As[wr * 64 + m * 16 + c][g * 8];
#pragma unroll
    for (int n = 0; n < 4; n++)
      bfr[n] = *(const s16x8*)&Bs[wc * 64 + n * 16 + c][g * 8];
#pragma unroll
    for (int m = 0; m < 4; m++)
#pragma unroll
      for (int n = 0; n < 4; n++)
        acc[m][n] = __builtin_amdgcn_mfma_f32_16x16x32_bf16(af[m], bfr[n],
                                                            acc[m][n], 0, 0, 0);
  }

  float bv4[4];
#pragma unroll
  for (int n = 0; n < 4; n++) bv4[n] = bias[n0 + wc * 64 + n * 16 + c];

  if (z == 0) {
#pragma unroll
    for (int m = 0; m < 4; m++) {
      const int row0 = m0 + wr * 64 + m * 16 + g * 4;
#pragma unroll
      for (int n = 0; n < 4; n++) {
        const int col = n0 + wc * 64 + n * 16 + c;
#pragma unroll
        for (int r = 0; r < 4; r++)
          ks[(row0 + r) * 256 + col] = f2bf(acc[m][n][r] + bv4[n]);
      }
    }
  } else {
#pragma unroll
    for (int m = 0; m < 4; m++) {
      const int row0 = m0 + wr * 64 + m * 16 + g * 4;
      const int bb = row0 >> 11, s = row0 & 2047;
#pragma unroll
      for (int n = 0; n < 4; n++) {
        const int col = n0 + wc * 64 + n * 16 + c;
        s16x4 pk;
#pragma unroll
        for (int r = 0; r < 4; r++) pk[r] = f2bf(acc[m][n][r] + bv4[n]);
        *(s16x4*)&vt[bb * 524288 + col * 2048 + s] = pk;  // vt[b][dv][s]
      }
    }
  }
}

// Fused Q-projection + flash attention with in-block KV split.
// grid (32 q-tiles, 8 batches), 512 threads = 8 waves:
//   waves 0-3 (group 0): kv tiles 0..15; waves 4-7 (group 1): kv tiles 16..31.
// Each wave owns 16 q-rows; groups merge (o,m,l) in LDS at the end.
__global__ __launch_bounds__(512, 2) void attn_fused(
    const float* __restrict__ q_in, const float* __restrict__ Wq,
    const float* __restrict__ bq, const short* __restrict__ ks,
    const short* __restrict__ vt, float* __restrict__ out) {
  const int b = blockIdx.y;
  const int q0 = blockIdx.x * 64;

  // LDS carve (159744 B total):
  //   0      KsA[64][264]   33792   (also Qlds in phase 0)
  //   33792  VsA[256][72]   36864   (also Wq^T tile [256][40] in phase 0)
  //   70656  KsB[64][264]   33792   (also X tile [64][40] in phase 0; merge Om)
  //   104448 VsB[256][72]   36864   (merge Om cont'd)
  //   141312 Ps[8][16][72]  18432   (merge Ml)
  __shared__ __align__(16) char smem[159744];
  short(*KsA)[264] = (short(*)[264])(smem);
  short(*VsA)[72] = (short(*)[72])(smem + 33792);
  short(*KsB)[264] = (short(*)[264])(smem + 70656);
  short(*VsB)[72] = (short(*)[72])(smem + 104448);
  short(*Ps)[16][72] = (short(*)[16][72])(smem + 141312);
  short(*Qlds)[264] = KsA;
  short(*Xs)[40] = (short(*)[40])(smem + 70656);
  short(*Wt)[40] = (short(*)[40])(smem + 33792);
  float(*Om)[260] = (float(*)[260])(smem + 70656);  // 64*260*4 = 66560
  float(*Ml)[2] = (float(*)[2])(smem + 141312);

  const int tid = threadIdx.x;
  const int lane = tid & 63;
  const int wid = tid >> 6;       // 0..7
  const int grp = tid >> 8;       // 0/1
  const int gtid = tid & 255;     // within group
  const int wq = wid & 3;         // q-row fragment (16 rows)
  const int g = lane >> 4, c = lane & 15;

  // ---- Phase 0: Q = q_in @ (Wq/16) + bq/16 -> Qlds (all 8 waves) ----
  {
    f32x4 accq[8];
#pragma unroll
    for (int f = 0; f < 8; f++) accq[f] = (f32x4)0.0f;
    const int xrow = tid >> 3, xseg = tid & 7;  // 64 rows x 32 fp32, 4 each
    const int wn = tid & 255, wkh = tid >> 8;   // W: 256 cols x 16 k each
    for (int kt = 0; kt < 16; ++kt) {
      const int k0 = kt * 32;
      f32x4 x0 = *(const f32x4*)&q_in[((b << 11) + q0 + xrow) * 512 + k0 + xseg * 4];
      float wv[16];
#pragma unroll
      for (int j = 0; j < 16; j++)
        wv[j] = Wq[(k0 + wkh * 16 + j) * 256 + wn] * 0.0625f;
      __syncthreads();  // previous k-step's fragment reads done
      s16x4 xc;
#pragma unroll
      for (int i = 0; i < 4; i++) xc[i] = f2bf(x0[i]);
      *(s16x4*)&Xs[xrow][xseg * 4] = xc;
      s16x8 w0, w1;
#pragma unroll
      for (int j = 0; j < 8; j++) {
        w0[j] = f2bf(wv[j]);
        w1[j] = f2bf(wv[8 + j]);
      }
      *(s16x8*)&Wt[wn][wkh * 16 + 0] = w0;
      *(s16x8*)&Wt[wn][wkh * 16 + 8] = w1;
      __syncthreads();
      const s16x8 xa = *(const s16x8*)&Xs[wq * 16 + c][g * 8];
#pragma unroll
      for (int f = 0; f < 8; f++) {
        const s16x8 wb = *(const s16x8*)&Wt[(grp * 8 + f) * 16 + c][g * 8];
        accq[f] = __builtin_amdgcn_mfma_f32_16x16x32_bf16(xa, wb, accq[f], 0, 0, 0);
      }
    }
    __syncthreads();  // all fragment reads done
#pragma unroll
    for (int f = 0; f < 8; f++) {
      const int col = (grp * 8 + f) * 16 + c;
      const float bb = bq[col] * 0.0625f;
#pragma unroll
      for (int r = 0; r < 4; r++)
        Qlds[wq * 16 + g * 4 + r][col] = f2bf(accq[f][r] + bb);
    }
    __syncthreads();
  }

  // hoist Q fragments (scaled)
  s16x8 qf[8];
#pragma unroll
  for (int d = 0; d < 8; d++)
    qf[d] = *(const s16x8*)&Qlds[wq * 16 + c][d * 32 + g * 8];

  short(*Ks)[264] = grp ? KsB : KsA;
  short(*Vs)[72] = grp ? VsB : VsA;
  const int ktbase = grp * 16;

  f32x4 o[16];
#pragma unroll
  for (int f = 0; f < 16; f++) o[f] = (f32x4)0.0f;
  float m_r[4] = {-1e30f, -1e30f, -1e30f, -1e30f};
  float l_r[4] = {0.f, 0.f, 0.f, 0.f};

  // prologue: load first tile into regs
  s16x8 kreg[8], vreg[8];
#pragma unroll
  for (int i = 0; i < 8; i++) {
    const int ch = gtid + i * 256;
    kreg[i] = *(const s16x8*)&ks[((b << 11) + ktbase * 64 + (ch >> 5)) * 256 +
                                 (ch & 31) * 8];
    vreg[i] = *(const s16x8*)&vt[b * 524288 + (ch >> 3) * 2048 + ktbase * 64 +
                                 (ch & 7) * 8];
  }

  for (int t = 0; t < 16; ++t) {
    __syncthreads();  // prev compute done (t=0: qf hoist done)
#pragma unroll
    for (int i = 0; i < 8; i++) {
      const int ch = gtid + i * 256;
      *(s16x8*)&Ks[ch >> 5][(ch & 31) * 8] = kreg[i];
      *(s16x8*)&Vs[ch >> 3][(ch & 7) * 8] = vreg[i];
    }
    if (t < 15) {  // prefetch next tile; latency hides under this tile's compute
      const int kt = ktbase + t + 1;
#pragma unroll
      for (int i = 0; i < 8; i++) {
        const int ch = gtid + i * 256;
        kreg[i] = *(const s16x8*)&ks[((b << 11) + kt * 64 + (ch >> 5)) * 256 +
                                     (ch & 31) * 8];
        vreg[i] = *(const s16x8*)&vt[b * 524288 + (ch >> 3) * 2048 + kt * 64 +
                                     (ch & 7) * 8];
      }
    }
    __syncthreads();  // tiles ready

    // S = Q K^T (16 q-rows x 64 kv per wave)
    f32x4 sf[4];
#pragma unroll
    for (int nf = 0; nf < 4; nf++) sf[nf] = (f32x4)0.0f;
#pragma unroll
    for (int d = 0; d < 8; d++) {
#pragma unroll
      for (int nf = 0; nf < 4; nf++) {
        const s16x8 kf = *(const s16x8*)&Ks[nf * 16 + c][d * 32 + g * 8];
        sf[nf] = __builtin_amdgcn_mfma_f32_16x16x32_bf16(qf[d], kf, sf[nf], 0, 0, 0);
      }
    }

    // online softmax (row g*4+r spread over 16 lanes c)
    float sc[4];
#pragma unroll
    for (int r = 0; r < 4; r++) {
      float mx = fmaxf(fmaxf(sf[0][r], sf[1][r]), fmaxf(sf[2][r], sf[3][r]));
      mx = fmaxf(mx, __shfl_xor(mx, 1, 64));
      mx = fmaxf(mx, __shfl_xor(mx, 2, 64));
      mx = fmaxf(mx, __shfl_xor(mx, 4, 64));
      mx = fmaxf(mx, __shfl_xor(mx, 8, 64));
      const float mn = fmaxf(m_r[r], mx);
      sc[r] = __expf(m_r[r] - mn);
      m_r[r] = mn;
      float sum = 0.f;
#pragma unroll
      for (int nf = 0; nf < 4; nf++) {
        const float p = __expf(sf[nf][r] - mn);
        sf[nf][r] = p;
        sum += p;
      }
      sum += __shfl_xor(sum, 1, 64);
      sum += __shfl_xor(sum, 2, 64);
      sum += __shfl_xor(sum, 4, 64);
      sum += __shfl_xor(sum, 8, 64);
      l_r[r] = l_r[r] * sc[r] + sum;
    }
#pragma unroll
    for (int f = 0; f < 16; f++)
#pragma unroll
      for (int r = 0; r < 4; r++) o[f][r] *= sc[r];

    // P -> wave-private LDS (no barrier: same-wave ds ordering)
#pragma unroll
    for (int nf = 0; nf < 4; nf++)
#pragma unroll
      for (int r = 0; r < 4; r++) Ps[wid][g * 4 + r][nf * 16 + c] = f2bf(sf[nf][r]);

    // O += P V
#pragma unroll
    for (int k2 = 0; k2 < 2; k2++) {
      const s16x8 pa = *(const s16x8*)&Ps[wid][c][k2 * 32 + g * 8];
#pragma unroll
      for (int f = 0; f < 16; f++) {
        const s16x8 vf = *(const s16x8*)&Vs[f * 16 + c][k2 * 32 + g * 8];
        o[f] = __builtin_amdgcn_mfma_f32_16x16x32_bf16(pa, vf, o[f], 0, 0, 0);
      }
    }
  }

  // ---- merge the two KV-half states and write out ----
  __syncthreads();  // all compute done; LDS free
  if (grp == 1) {
#pragma unroll
    for (int f = 0; f < 16; f++)
#pragma unroll
      for (int r = 0; r < 4; r++)
        Om[wq * 16 + g * 4 + r][f * 16 + c] = o[f][r];
    if (c == 0) {
#pragma unroll
      for (int r = 0; r < 4; r++) {
        Ml[wq * 16 + g * 4 + r][0] = m_r[r];
        Ml[wq * 16 + g * 4 + r][1] = l_r[r];
      }
    }
  }
  __syncthreads();
  if (grp == 0) {
    float e0v[4], e1v[4], inv[4];
#pragma unroll
    for (int r = 0; r < 4; r++) {
      const int rw = wq * 16 + g * 4 + r;
      const float m1 = Ml[rw][0], l1 = Ml[rw][1];
      const float ms = fmaxf(m_r[r], m1);
      e0v[r] = __expf(m_r[r] - ms);
      e1v[r] = __expf(m1 - ms);
      inv[r] = 1.0f / (l_r[r] * e0v[r] + l1 * e1v[r]);
    }
#pragma unroll
    for (int f = 0; f < 16; f++) {
#pragma unroll
      for (int r = 0; r < 4; r++) {
        const int rw = wq * 16 + g * 4 + r;
        const int col = f * 16 + c;
        out[((b << 11) + q0 + rw) * 256 + col] =
            (o[f][r] * e0v[r] + Om[rw][col] * e1v[r]) * inv[r];
      }
    }
  }
}

extern "C" void kernel_launch(void* const* d_in, const int* in_sizes, int n_in,
                              void* d_out, int out_size, void* d_ws,
                              size_t ws_size, hipStream_t stream) {
  const float* q_in = (const float*)d_in[0];
  const float* k_in = (const float*)d_in[1];
  const float* v_in = (const float*)d_in[2];
  const float* Wq = (const float*)d_in[3];
  const float* bq = (const float*)d_in[4];
  const float* Wk = (const float*)d_in[5];
  const float* bk = (const float*)d_in[6];
  const float* Wv = (const float*)d_in[7];
  const float* bv = (const float*)d_in[8];
  float* out = (float*)d_out;

  char* ws = (char*)d_ws;
  short* ksb = (short*)ws;                // 8 MB [b][s][dk] bf16
  short* vtb = (short*)(ws + (8 << 20));  // 8 MB [b][dv][s] bf16

  proj_kv<<<dim3(2, 128, 2), dim3(256), 0, stream>>>(k_in, v_in, bk, bv, Wk, Wv,
                                                     ksb, vtb);
  attn_fused<<<dim3(32, 8), dim3(512), 0, stream>>>(q_in, Wq, bq, ksb, vtb, out);
}

// Round 4
// 131.289 us; speedup vs baseline: 1.1165x; 1.1156x over previous
//
#include <hip/hip_runtime.h>
#include <hip/hip_bf16.h>

// SingleAttention: q/k/v = X@W+b (fp32 in), out = softmax(q k^T/16) v, fp32 out.
// B=8 S=2048 D_IN=512 D_K=D_V=256.
// ws usage: EXACTLY 16 MB = ks bf16 [8][2048][256] (8MB) + vt bf16 [8][256][2048] (8MB).

typedef __attribute__((ext_vector_type(4))) float f32x4;
typedef __attribute__((ext_vector_type(8))) short s16x8;
typedef __attribute__((ext_vector_type(4))) short s16x4;

static __device__ __forceinline__ short f2bf(float x) {
  __hip_bfloat16 h = __float2bfloat16(x);
  return *reinterpret_cast<short*>(&h);
}

// K/V projection: P[16384,256] = X @ W + b -> bf16.
// z=0 -> ks row-major [b][s][dk]; z=1 -> vt transposed [b][dv][s].
__global__ __launch_bounds__(256) void proj_kv(
    const float* __restrict__ k_in, const float* __restrict__ v_in,
    const float* __restrict__ bk, const float* __restrict__ bv,
    const float* __restrict__ Wk, const float* __restrict__ Wv,
    short* __restrict__ ks, short* __restrict__ vt) {
  const int z = blockIdx.z;
  const float* X = z == 0 ? k_in : v_in;
  const float* W = z == 0 ? Wk : Wv;
  const float* bias = z == 0 ? bk : bv;
  const int n0 = blockIdx.x * 128;
  const int m0 = blockIdx.y * 128;

  __shared__ short As[128][40];
  __shared__ short Bs[128][40];

  const int tid = threadIdx.x;
  const int lane = tid & 63;
  const int wid = tid >> 6;
  const int wr = wid >> 1, wc = wid & 1;
  const int g = lane >> 4, c = lane & 15;

  f32x4 acc[4][4];
#pragma unroll
  for (int m = 0; m < 4; m++)
#pragma unroll
    for (int n = 0; n < 4; n++) acc[m][n] = (f32x4)0.0f;

  const int arow = tid >> 1, ahalf = tid & 1;
  const int bn = tid & 127, bhalf = tid >> 7;

  for (int kt = 0; kt < 16; ++kt) {
    const int k0 = kt * 32;
    const float* ap = &X[(m0 + arow) * 512 + k0 + ahalf * 16];
    f32x4 a0 = *(const f32x4*)(ap + 0);
    f32x4 a1 = *(const f32x4*)(ap + 4);
    f32x4 a2 = *(const f32x4*)(ap + 8);
    f32x4 a3 = *(const f32x4*)(ap + 12);
    float wv[16];
#pragma unroll
    for (int j = 0; j < 16; j++)
      wv[j] = W[(k0 + bhalf * 16 + j) * 256 + n0 + bn];
    __syncthreads();
    s16x8 ac0, ac1, w0, w1;
#pragma unroll
    for (int i = 0; i < 4; i++) {
      ac0[i] = f2bf(a0[i]);
      ac0[i + 4] = f2bf(a1[i]);
      ac1[i] = f2bf(a2[i]);
      ac1[i + 4] = f2bf(a3[i]);
    }
#pragma unroll
    for (int j = 0; j < 8; j++) {
      w0[j] = f2bf(wv[j]);
      w1[j] = f2bf(wv[8 + j]);
    }
    *(s16x8*)&As[arow][ahalf * 16 + 0] = ac0;
    *(s16x8*)&As[arow][ahalf * 16 + 8] = ac1;
    *(s16x8*)&Bs[bn][bhalf * 16 + 0] = w0;
    *(s16x8*)&Bs[bn][bhalf * 16 + 8] = w1;
    __syncthreads();
    s16x8 af[4], bfr[4];
#pragma unroll
    for (int m = 0; m < 4; m++)
      af[m] = *(const s16x8*)&As[wr * 64 + m * 16 + c][g * 8];
#pragma unroll
    for (int n = 0; n < 4; n++)
      bfr[n] = *(const s16x8*)&Bs[wc * 64 + n * 16 + c][g * 8];
#pragma unroll
    for (int m = 0; m < 4; m++)
#pragma unroll
      for (int n = 0; n < 4; n++)
        acc[m][n] = __builtin_amdgcn_mfma_f32_16x16x32_bf16(af[m], bfr[n],
                                                            acc[m][n], 0, 0, 0);
  }

  float bv4[4];
#pragma unroll
  for (int n = 0; n < 4; n++) bv4[n] = bias[n0 + wc * 64 + n * 16 + c];

  if (z == 0) {
#pragma unroll
    for (int m = 0; m < 4; m++) {
      const int row0 = m0 + wr * 64 + m * 16 + g * 4;
#pragma unroll
      for (int n = 0; n < 4; n++) {
        const int col = n0 + wc * 64 + n * 16 + c;
#pragma unroll
        for (int r = 0; r < 4; r++)
          ks[(row0 + r) * 256 + col] = f2bf(acc[m][n][r] + bv4[n]);
      }
    }
  } else {
#pragma unroll
    for (int m = 0; m < 4; m++) {
      const int row0 = m0 + wr * 64 + m * 16 + g * 4;
      const int bb = row0 >> 11, s = row0 & 2047;
#pragma unroll
      for (int n = 0; n < 4; n++) {
        const int col = n0 + wc * 64 + n * 16 + c;
        s16x4 pk;
#pragma unroll
        for (int r = 0; r < 4; r++) pk[r] = f2bf(acc[m][n][r] + bv4[n]);
        *(s16x4*)&vt[bb * 524288 + col * 2048 + s] = pk;  // vt[b][dv][s]
      }
    }
  }
}

// Fused Q-projection + flash attention with in-block KV split.
// Flat grid 256 blocks: b = bid&7 (XCD = bid%8 -> whole batch on one XCD,
// K/V 2MB fits the 4MB per-XCD L2), q0 = (bid>>3)*64.
// 512 threads = 8 waves: waves 0-3 kv tiles 0..15; waves 4-7 kv tiles 16..31.
// Loop order per tile: {barrier; LDS-write(regs); barrier; issue loads t+1;
// compute t} so the t+1 loads are in flight under compute t (drained at the
// next loop-top barrier).
__global__ __launch_bounds__(512, 2) void attn_fused(
    const float* __restrict__ q_in, const float* __restrict__ Wq,
    const float* __restrict__ bq, const short* __restrict__ ks,
    const short* __restrict__ vt, float* __restrict__ out) {
  const int bid = blockIdx.x;
  const int b = bid & 7;
  const int q0 = (bid >> 3) * 64;

  // LDS carve (159744 B total):
  //   0      KsA[64][264]   33792   (also Qlds in phase 0)
  //   33792  VsA[256][72]   36864   (also Wq^T tile [256][40] in phase 0)
  //   70656  KsB[64][264]   33792   (also X tile [64][40] in phase 0; merge Om)
  //   104448 VsB[256][72]   36864   (merge Om cont'd)
  //   141312 Ps[8][16][72]  18432   (merge Ml)
  __shared__ __align__(16) char smem[159744];
  short(*KsA)[264] = (short(*)[264])(smem);
  short(*VsA)[72] = (short(*)[72])(smem + 33792);
  short(*KsB)[264] = (short(*)[264])(smem + 70656);
  short(*VsB)[72] = (short(*)[72])(smem + 104448);
  short(*Ps)[16][72] = (short(*)[16][72])(smem + 141312);
  short(*Qlds)[264] = KsA;
  short(*Xs)[40] = (short(*)[40])(smem + 70656);
  short(*Wt)[40] = (short(*)[40])(smem + 33792);
  float(*Om)[260] = (float(*)[260])(smem + 70656);  // 64*260*4 = 66560
  float(*Ml)[2] = (float(*)[2])(smem + 141312);

  const int tid = threadIdx.x;
  const int lane = tid & 63;
  const int wid = tid >> 6;       // 0..7
  const int grp = tid >> 8;       // 0/1
  const int gtid = tid & 255;     // within group
  const int wq = wid & 3;         // q-row fragment (16 rows)
  const int g = lane >> 4, c = lane & 15;

  // ---- Phase 0: Q = q_in @ (Wq/16) + bq/16 -> Qlds (all 8 waves) ----
  {
    f32x4 accq[8];
#pragma unroll
    for (int f = 0; f < 8; f++) accq[f] = (f32x4)0.0f;
    const int xrow = tid >> 3, xseg = tid & 7;  // 64 rows x 32 fp32, 4 each
    const int wn = tid & 255, wkh = tid >> 8;   // W: 256 cols x 16 k each
    for (int kt = 0; kt < 16; ++kt) {
      const int k0 = kt * 32;
      f32x4 x0 = *(const f32x4*)&q_in[((b << 11) + q0 + xrow) * 512 + k0 + xseg * 4];
      float wv[16];
#pragma unroll
      for (int j = 0; j < 16; j++)
        wv[j] = Wq[(k0 + wkh * 16 + j) * 256 + wn] * 0.0625f;
      __syncthreads();  // previous k-step's fragment reads done
      s16x4 xc;
#pragma unroll
      for (int i = 0; i < 4; i++) xc[i] = f2bf(x0[i]);
      *(s16x4*)&Xs[xrow][xseg * 4] = xc;
      s16x8 w0, w1;
#pragma unroll
      for (int j = 0; j < 8; j++) {
        w0[j] = f2bf(wv[j]);
        w1[j] = f2bf(wv[8 + j]);
      }
      *(s16x8*)&Wt[wn][wkh * 16 + 0] = w0;
      *(s16x8*)&Wt[wn][wkh * 16 + 8] = w1;
      __syncthreads();
      const s16x8 xa = *(const s16x8*)&Xs[wq * 16 + c][g * 8];
#pragma unroll
      for (int f = 0; f < 8; f++) {
        const s16x8 wb = *(const s16x8*)&Wt[(grp * 8 + f) * 16 + c][g * 8];
        accq[f] = __builtin_amdgcn_mfma_f32_16x16x32_bf16(xa, wb, accq[f], 0, 0, 0);
      }
    }
    __syncthreads();  // all fragment reads done
#pragma unroll
    for (int f = 0; f < 8; f++) {
      const int col = (grp * 8 + f) * 16 + c;
      const float bb = bq[col] * 0.0625f;
#pragma unroll
      for (int r = 0; r < 4; r++)
        Qlds[wq * 16 + g * 4 + r][col] = f2bf(accq[f][r] + bb);
    }
    __syncthreads();
  }

  // hoist Q fragments (scaled)
  s16x8 qf[8];
#pragma unroll
  for (int d = 0; d < 8; d++)
    qf[d] = *(const s16x8*)&Qlds[wq * 16 + c][d * 32 + g * 8];

  short(*Ks)[264] = grp ? KsB : KsA;
  short(*Vs)[72] = grp ? VsB : VsA;
  const int ktbase = grp * 16;

  f32x4 o[16];
#pragma unroll
  for (int f = 0; f < 16; f++) o[f] = (f32x4)0.0f;
  float m_r[4] = {-1e30f, -1e30f, -1e30f, -1e30f};
  float l_r[4] = {0.f, 0.f, 0.f, 0.f};

  // prologue: load first tile into regs
  s16x8 kreg[8], vreg[8];
#pragma unroll
  for (int i = 0; i < 8; i++) {
    const int ch = gtid + i * 256;
    kreg[i] = *(const s16x8*)&ks[((b << 11) + ktbase * 64 + (ch >> 5)) * 256 +
                                 (ch & 31) * 8];
    vreg[i] = *(const s16x8*)&vt[b * 524288 + (ch >> 3) * 2048 + ktbase * 64 +
                                 (ch & 7) * 8];
  }

  for (int t = 0; t < 16; ++t) {
    __syncthreads();  // prev compute's LDS reads done (t=0: qf hoist done);
                      // also drains the in-flight loads for this tile
#pragma unroll
    for (int i = 0; i < 8; i++) {
      const int ch = gtid + i * 256;
      *(s16x8*)&Ks[ch >> 5][(ch & 31) * 8] = kreg[i];
      *(s16x8*)&Vs[ch >> 3][(ch & 7) * 8] = vreg[i];
    }
    __syncthreads();  // tiles ready (no outstanding vmem here)

    if (t < 15) {  // issue next-tile loads; they fly under this tile's compute
      const int kt = ktbase + t + 1;
#pragma unroll
      for (int i = 0; i < 8; i++) {
        const int ch = gtid + i * 256;
        kreg[i] = *(const s16x8*)&ks[((b << 11) + kt * 64 + (ch >> 5)) * 256 +
                                     (ch & 31) * 8];
        vreg[i] = *(const s16x8*)&vt[b * 524288 + (ch >> 3) * 2048 + kt * 64 +
                                     (ch & 7) * 8];
      }
    }

    // S = Q K^T (16 q-rows x 64 kv per wave)
    f32x4 sf[4];
#pragma unroll
    for (int nf = 0; nf < 4; nf++) sf[nf] = (f32x4)0.0f;
#pragma unroll
    for (int d = 0; d < 8; d++) {
#pragma unroll
      for (int nf = 0; nf < 4; nf++) {
        const s16x8 kf = *(const s16x8*)&Ks[nf * 16 + c][d * 32 + g * 8];
        sf[nf] = __builtin_amdgcn_mfma_f32_16x16x32_bf16(qf[d], kf, sf[nf], 0, 0, 0);
      }
    }

    // online softmax (row g*4+r spread over 16 lanes c)
    float sc[4];
#pragma unroll
    for (int r = 0; r < 4; r++) {
      float mx = fmaxf(fmaxf(sf[0][r], sf[1][r]), fmaxf(sf[2][r], sf[3][r]));
      mx = fmaxf(mx, __shfl_xor(mx, 1, 64));
      mx = fmaxf(mx, __shfl_xor(mx, 2, 64));
      mx = fmaxf(mx, __shfl_xor(mx, 4, 64));
      mx = fmaxf(mx, __shfl_xor(mx, 8, 64));
      const float mn = fmaxf(m_r[r], mx);
      sc[r] = __expf(m_r[r] - mn);
      m_r[r] = mn;
      float sum = 0.f;
#pragma unroll
      for (int nf = 0; nf < 4; nf++) {
        const float p = __expf(sf[nf][r] - mn);
        sf[nf][r] = p;
        sum += p;
      }
      sum += __shfl_xor(sum, 1, 64);
      sum += __shfl_xor(sum, 2, 64);
      sum += __shfl_xor(sum, 4, 64);
      sum += __shfl_xor(sum, 8, 64);
      l_r[r] = l_r[r] * sc[r] + sum;
    }
#pragma unroll
    for (int f = 0; f < 16; f++)
#pragma unroll
      for (int r = 0; r < 4; r++) o[f][r] *= sc[r];

    // P -> wave-private LDS (no barrier: same-wave ds ordering)
#pragma unroll
    for (int nf = 0; nf < 4; nf++)
#pragma unroll
      for (int r = 0; r < 4; r++) Ps[wid][g * 4 + r][nf * 16 + c] = f2bf(sf[nf][r]);

    // O += P V
#pragma unroll
    for (int k2 = 0; k2 < 2; k2++) {
      const s16x8 pa = *(const s16x8*)&Ps[wid][c][k2 * 32 + g * 8];
#pragma unroll
      for (int f = 0; f < 16; f++) {
        const s16x8 vf = *(const s16x8*)&Vs[f * 16 + c][k2 * 32 + g * 8];
        o[f] = __builtin_amdgcn_mfma_f32_16x16x32_bf16(pa, vf, o[f], 0, 0, 0);
      }
    }
  }

  // ---- merge the two KV-half states and write out ----
  __syncthreads();  // all compute done; LDS free
  if (grp == 1) {
#pragma unroll
    for (int f = 0; f < 16; f++)
#pragma unroll
      for (int r = 0; r < 4; r++)
        Om[wq * 16 + g * 4 + r][f * 16 + c] = o[f][r];
    if (c == 0) {
#pragma unroll
      for (int r = 0; r < 4; r++) {
        Ml[wq * 16 + g * 4 + r][0] = m_r[r];
        Ml[wq * 16 + g * 4 + r][1] = l_r[r];
      }
    }
  }
  __syncthreads();
  if (grp == 0) {
    float e0v[4], e1v[4], inv[4];
#pragma unroll
    for (int r = 0; r < 4; r++) {
      const int rw = wq * 16 + g * 4 + r;
      const float m1 = Ml[rw][0], l1 = Ml[rw][1];
      const float ms = fmaxf(m_r[r], m1);
      e0v[r] = __expf(m_r[r] - ms);
      e1v[r] = __expf(m1 - ms);
      inv[r] = 1.0f / (l_r[r] * e0v[r] + l1 * e1v[r]);
    }
#pragma unroll
    for (int f = 0; f < 16; f++) {
#pragma unroll
      for (int r = 0; r < 4; r++) {
        const int rw = wq * 16 + g * 4 + r;
        const int col = f * 16 + c;
        out[((b << 11) + q0 + rw) * 256 + col] =
            (o[f][r] * e0v[r] + Om[rw][col] * e1v[r]) * inv[r];
      }
    }
  }
}

extern "C" void kernel_launch(void* const* d_in, const int* in_sizes, int n_in,
                              void* d_out, int out_size, void* d_ws,
                              size_t ws_size, hipStream_t stream) {
  const float* q_in = (const float*)d_in[0];
  const float* k_in = (const float*)d_in[1];
  const float* v_in = (const float*)d_in[2];
  const float* Wq = (const float*)d_in[3];
  const float* bq = (const float*)d_in[4];
  const float* Wk = (const float*)d_in[5];
  const float* bk = (const float*)d_in[6];
  const float* Wv = (const float*)d_in[7];
  const float* bv = (const float*)d_in[8];
  float* out = (float*)d_out;

  char* ws = (char*)d_ws;
  short* ksb = (short*)ws;                // 8 MB [b][s][dk] bf16
  short* vtb = (short*)(ws + (8 << 20));  // 8 MB [b][dv][s] bf16

  proj_kv<<<dim3(2, 128, 2), dim3(256), 0, stream>>>(k_in, v_in, bk, bv, Wk, Wv,
                                                     ksb, vtb);
  attn_fused<<<dim3(256), dim3(512), 0, stream>>>(q_in, Wq, bq, ksb, vtb, out);
}

// Round 6
// 125.186 us; speedup vs baseline: 1.1710x; 1.0488x over previous
//
#include <hip/hip_runtime.h>
#include <hip/hip_bf16.h>

// SingleAttention: q/k/v = X@W+b (fp32 in), out = softmax(q k^T/16) v, fp32 out.
// B=8 S=2048 D_IN=512 D_K=D_V=256.
// ws: EXACTLY 16 MB = ks bf16 [8][2048][256] (8MB) + vt bf16 [8][dv=256][s=2048] (8MB).
// Q (bf16, scaled by 1/16) is stashed in the first 512B of each d_out row
// (stride 512 shorts); each attn block reads only its own rows, then
// overwrites them in its epilogue.

typedef __attribute__((ext_vector_type(4))) float f32x4;
typedef __attribute__((ext_vector_type(8))) short s16x8;
typedef __attribute__((ext_vector_type(4))) short s16x4;

static __device__ __forceinline__ short f2bf(float x) {
  __hip_bfloat16 h = __float2bfloat16(x);
  return *reinterpret_cast<short*>(&h);
}

// Projection: P[16384,256] = X @ W + b -> bf16.
// z=0 -> qs (scaled 1/16), row stride 512; z=1 -> ks, stride 256;
// z=2 -> vt transposed [b][dv][s].
__global__ __launch_bounds__(256) void proj3(
    const float* __restrict__ q_in, const float* __restrict__ k_in,
    const float* __restrict__ v_in, const float* __restrict__ bq,
    const float* __restrict__ bk, const float* __restrict__ bv,
    const float* __restrict__ Wq, const float* __restrict__ Wk,
    const float* __restrict__ Wv, short* __restrict__ qs,
    short* __restrict__ ks, short* __restrict__ vt) {
  const int z = blockIdx.z;
  const float* X = z == 0 ? q_in : z == 1 ? k_in : v_in;
  const float* W = z == 0 ? Wq : z == 1 ? Wk : Wv;
  const float* bias = z == 0 ? bq : z == 1 ? bk : bv;
  const float sc = z == 0 ? 0.0625f : 1.0f;
  const int n0 = blockIdx.x * 128;
  const int m0 = blockIdx.y * 128;

  __shared__ short As[128][40];
  __shared__ short Bs[128][40];

  const int tid = threadIdx.x;
  const int lane = tid & 63;
  const int wid = tid >> 6;
  const int wr = wid >> 1, wc = wid & 1;
  const int g = lane >> 4, c = lane & 15;

  f32x4 acc[4][4];
#pragma unroll
  for (int m = 0; m < 4; m++)
#pragma unroll
    for (int n = 0; n < 4; n++) acc[m][n] = (f32x4)0.0f;

  const int arow = tid >> 1, ahalf = tid & 1;
  const int bn = tid & 127, bhalf = tid >> 7;

  for (int kt = 0; kt < 16; ++kt) {
    const int k0 = kt * 32;
    const float* ap = &X[(m0 + arow) * 512 + k0 + ahalf * 16];
    f32x4 a0 = *(const f32x4*)(ap + 0);
    f32x4 a1 = *(const f32x4*)(ap + 4);
    f32x4 a2 = *(const f32x4*)(ap + 8);
    f32x4 a3 = *(const f32x4*)(ap + 12);
    float wv[16];
#pragma unroll
    for (int j = 0; j < 16; j++)
      wv[j] = W[(k0 + bhalf * 16 + j) * 256 + n0 + bn] * sc;
    __syncthreads();
    s16x8 ac0, ac1, w0, w1;
#pragma unroll
    for (int i = 0; i < 4; i++) {
      ac0[i] = f2bf(a0[i]);
      ac0[i + 4] = f2bf(a1[i]);
      ac1[i] = f2bf(a2[i]);
      ac1[i + 4] = f2bf(a3[i]);
    }
#pragma unroll
    for (int j = 0; j < 8; j++) {
      w0[j] = f2bf(wv[j]);
      w1[j] = f2bf(wv[8 + j]);
    }
    *(s16x8*)&As[arow][ahalf * 16 + 0] = ac0;
    *(s16x8*)&As[arow][ahalf * 16 + 8] = ac1;
    *(s16x8*)&Bs[bn][bhalf * 16 + 0] = w0;
    *(s16x8*)&Bs[bn][bhalf * 16 + 8] = w1;
    __syncthreads();
    s16x8 af[4], bfr[4];
#pragma unroll
    for (int m = 0; m < 4; m++)
      af[m] = *(const s16x8*)&As[wr * 64 + m * 16 + c][g * 8];
#pragma unroll
    for (int n = 0; n < 4; n++)
      bfr[n] = *(const s16x8*)&Bs[wc * 64 + n * 16 + c][g * 8];
#pragma unroll
    for (int m = 0; m < 4; m++)
#pragma unroll
      for (int n = 0; n < 4; n++)
        acc[m][n] = __builtin_amdgcn_mfma_f32_16x16x32_bf16(af[m], bfr[n],
                                                            acc[m][n], 0, 0, 0);
  }

  float bv4[4];
#pragma unroll
  for (int n = 0; n < 4; n++) bv4[n] = bias[n0 + wc * 64 + n * 16 + c] * sc;

  if (z <= 1) {
    short* outp = z == 0 ? qs : ks;
    const int ostr = z == 0 ? 512 : 256;
#pragma unroll
    for (int m = 0; m < 4; m++) {
      const int row0 = m0 + wr * 64 + m * 16 + g * 4;
#pragma unroll
      for (int n = 0; n < 4; n++) {
        const int col = n0 + wc * 64 + n * 16 + c;
#pragma unroll
        for (int r = 0; r < 4; r++)
          outp[(row0 + r) * ostr + col] = f2bf(acc[m][n][r] + bv4[n]);
      }
    }
  } else {
#pragma unroll
    for (int m = 0; m < 4; m++) {
      const int row0 = m0 + wr * 64 + m * 16 + g * 4;
      const int bb = row0 >> 11, s = row0 & 2047;
#pragma unroll
      for (int n = 0; n < 4; n++) {
        const int col = n0 + wc * 64 + n * 16 + c;
        s16x4 pk;
#pragma unroll
        for (int r = 0; r < 4; r++) pk[r] = f2bf(acc[m][n][r] + bv4[n]);
        *(s16x4*)&vt[bb * 524288 + col * 2048 + s] = pk;  // vt[b][dv][s]
      }
    }
  }
}

// Flash attention with in-block KV split. Flat grid 256: b = bid&7 (XCD-local
// batch -> K/V L2-resident), q0 = (bid>>3)*64. 512 threads = 8 waves:
// waves 0-3: kv tiles 0..15; waves 4-7: kv tiles 16..31. Q read from d_out
// rows (bf16, stride 512 shorts), final O overwrites the same rows.
__global__ __launch_bounds__(512, 2) void attn_fused(
    const short* __restrict__ qs, const short* __restrict__ ks,
    const short* __restrict__ vt, float* __restrict__ out) {
  const int bid = blockIdx.x;
  const int b = bid & 7;
  const int q0 = (bid >> 3) * 64;

  // LDS carve (159744 B):
  //   0      KsA[64][264]   33792   (merge: Om overlay)
  //   33792  VsA[256][72]   36864   (merge: Om cont'd)
  //   70656  KsB[64][264]   33792   (merge: Ml overlay)
  //   104448 VsB[256][72]   36864
  //   141312 Ps[8][16][72]  18432   (ends at 159744)
  __shared__ __align__(16) char smem[159744];
  short(*KsA)[264] = (short(*)[264])(smem);
  short(*VsA)[72] = (short(*)[72])(smem + 33792);
  short(*KsB)[264] = (short(*)[264])(smem + 70656);
  short(*VsB)[72] = (short(*)[72])(smem + 104448);
  short(*Ps)[16][72] = (short(*)[16][72])(smem + 141312);
  float(*Om)[260] = (float(*)[260])(smem);        // 64*260*4 = 66560 <= 70656
  float(*Ml)[2] = (float(*)[2])(smem + 70656);

  const int tid = threadIdx.x;
  const int lane = tid & 63;
  const int wid = tid >> 6;    // 0..7
  const int grp = tid >> 8;    // 0/1
  const int gtid = tid & 255;  // within group
  const int wq = wid & 3;      // q-row fragment (16 rows)
  const int g = lane >> 4, c = lane & 15;

  // hoist Q fragments from global (bf16, pre-scaled by 1/16)
  s16x8 qf[8];
  {
    const int qrow = (b << 11) + q0 + wq * 16 + c;
#pragma unroll
    for (int d = 0; d < 8; d++)
      qf[d] = *(const s16x8*)&qs[qrow * 512 + d * 32 + g * 8];
  }

  short(*Ks)[264] = grp ? KsB : KsA;
  short(*Vs)[72] = grp ? VsB : VsA;
  const int ktbase = grp * 16;

  f32x4 o[16];
#pragma unroll
  for (int f = 0; f < 16; f++) o[f] = (f32x4)0.0f;
  float m_r[4] = {-1e30f, -1e30f, -1e30f, -1e30f};
  float l_r[4] = {0.f, 0.f, 0.f, 0.f};

  // prologue: load first tile into regs
  s16x8 kreg[8], vreg[8];
#pragma unroll
  for (int i = 0; i < 8; i++) {
    const int ch = gtid + i * 256;
    kreg[i] = *(const s16x8*)&ks[((b << 11) + ktbase * 64 + (ch >> 5)) * 256 +
                                 (ch & 31) * 8];
    vreg[i] = *(const s16x8*)&vt[b * 524288 + (ch >> 3) * 2048 + ktbase * 64 +
                                 (ch & 7) * 8];
  }

  for (int t = 0; t < 16; ++t) {
    __syncthreads();  // prev compute's LDS reads done
#pragma unroll
    for (int i = 0; i < 8; i++) {
      const int ch = gtid + i * 256;
      *(s16x8*)&Ks[ch >> 5][(ch & 31) * 8] = kreg[i];
      *(s16x8*)&Vs[ch >> 3][(ch & 7) * 8] = vreg[i];
    }
    __syncthreads();  // tiles ready

    if (t < 15) {  // next-tile loads fly under this tile's compute
      const int kt = ktbase + t + 1;
#pragma unroll
      for (int i = 0; i < 8; i++) {
        const int ch = gtid + i * 256;
        kreg[i] = *(const s16x8*)&ks[((b << 11) + kt * 64 + (ch >> 5)) * 256 +
                                     (ch & 31) * 8];
        vreg[i] = *(const s16x8*)&vt[b * 524288 + (ch >> 3) * 2048 + kt * 64 +
                                     (ch & 7) * 8];
      }
    }

    // S = Q K^T (16 q-rows x 64 kv per wave)
    f32x4 sf[4];
#pragma unroll
    for (int nf = 0; nf < 4; nf++) sf[nf] = (f32x4)0.0f;
    __builtin_amdgcn_s_setprio(1);
#pragma unroll
    for (int d = 0; d < 8; d++) {
#pragma unroll
      for (int nf = 0; nf < 4; nf++) {
        const s16x8 kf = *(const s16x8*)&Ks[nf * 16 + c][d * 32 + g * 8];
        sf[nf] = __builtin_amdgcn_mfma_f32_16x16x32_bf16(qf[d], kf, sf[nf], 0, 0, 0);
      }
    }
    __builtin_amdgcn_s_setprio(0);

    // online softmax with defer-max (THR=8): row g*4+r spread over lanes c
    float mx[4];
#pragma unroll
    for (int r = 0; r < 4; r++) {
      float m0 = fmaxf(fmaxf(sf[0][r], sf[1][r]), fmaxf(sf[2][r], sf[3][r]));
      m0 = fmaxf(m0, __shfl_xor(m0, 1, 64));
      m0 = fmaxf(m0, __shfl_xor(m0, 2, 64));
      m0 = fmaxf(m0, __shfl_xor(m0, 4, 64));
      m0 = fmaxf(m0, __shfl_xor(m0, 8, 64));
      mx[r] = m0;
    }
    const bool grow = (mx[0] > m_r[0] + 8.f) | (mx[1] > m_r[1] + 8.f) |
                      (mx[2] > m_r[2] + 8.f) | (mx[3] > m_r[3] + 8.f);
    if (__any(grow)) {  // wave-uniform
#pragma unroll
      for (int r = 0; r < 4; r++) {
        const float mn = fmaxf(m_r[r], mx[r]);
        const float scr = __expf(m_r[r] - mn);
        m_r[r] = mn;
        l_r[r] *= scr;
#pragma unroll
        for (int f = 0; f < 16; f++) o[f][r] *= scr;
      }
    }
#pragma unroll
    for (int r = 0; r < 4; r++) {
      float sum = 0.f;
#pragma unroll
      for (int nf = 0; nf < 4; nf++) {
        const float p = __expf(sf[nf][r] - m_r[r]);
        sf[nf][r] = p;
        sum += p;
      }
      sum += __shfl_xor(sum, 1, 64);
      sum += __shfl_xor(sum, 2, 64);
      sum += __shfl_xor(sum, 4, 64);
      sum += __shfl_xor(sum, 8, 64);
      l_r[r] += sum;
    }

    // P -> wave-private LDS (no barrier: same-wave ds ordering)
#pragma unroll
    for (int nf = 0; nf < 4; nf++)
#pragma unroll
      for (int r = 0; r < 4; r++) Ps[wid][g * 4 + r][nf * 16 + c] = f2bf(sf[nf][r]);

    // O += P V
    __builtin_amdgcn_s_setprio(1);
#pragma unroll
    for (int k2 = 0; k2 < 2; k2++) {
      const s16x8 pa = *(const s16x8*)&Ps[wid][c][k2 * 32 + g * 8];
#pragma unroll
      for (int f = 0; f < 16; f++) {
        const s16x8 vf = *(const s16x8*)&Vs[f * 16 + c][k2 * 32 + g * 8];
        o[f] = __builtin_amdgcn_mfma_f32_16x16x32_bf16(pa, vf, o[f], 0, 0, 0);
      }
    }
    __builtin_amdgcn_s_setprio(0);
  }

  // ---- merge the two KV-half states and write out ----
  __syncthreads();  // all compute done; LDS free
  if (grp == 1) {
#pragma unroll
    for (int f = 0; f < 16; f++)
#pragma unroll
      for (int r = 0; r < 4; r++)
        Om[wq * 16 + g * 4 + r][f * 16 + c] = o[f][r];
    if (c == 0) {
#pragma unroll
      for (int r = 0; r < 4; r++) {
        Ml[wq * 16 + g * 4 + r][0] = m_r[r];
        Ml[wq * 16 + g * 4 + r][1] = l_r[r];
      }
    }
  }
  __syncthreads();
  if (grp == 0) {
    float e0v[4], e1v[4], inv[4];
#pragma unroll
    for (int r = 0; r < 4; r++) {
      const int rw = wq * 16 + g * 4 + r;
      const float m1 = Ml[rw][0], l1 = Ml[rw][1];
      const float ms = fmaxf(m_r[r], m1);
      e0v[r] = __expf(m_r[r] - ms);
      e1v[r] = __expf(m1 - ms);
      inv[r] = 1.0f / (l_r[r] * e0v[r] + l1 * e1v[r]);
    }
#pragma unroll
    for (int f = 0; f < 16; f++) {
#pragma unroll
      for (int r = 0; r < 4; r++) {
        const int rw = wq * 16 + g * 4 + r;
        const int col = f * 16 + c;
        out[((b << 11) + q0 + rw) * 256 + col] =
            (o[f][r] * e0v[r] + Om[rw][col] * e1v[r]) * inv[r];
      }
    }
  }
}

extern "C" void kernel_launch(void* const* d_in, const int* in_sizes, int n_in,
                              void* d_out, int out_size, void* d_ws,
                              size_t ws_size, hipStream_t stream) {
  const float* q_in = (const float*)d_in[0];
  const float* k_in = (const float*)d_in[1];
  const float* v_in = (const float*)d_in[2];
  const float* Wq = (const float*)d_in[3];
  const float* bq = (const float*)d_in[4];
  const float* Wk = (const float*)d_in[5];
  const float* bk = (const float*)d_in[6];
  const float* Wv = (const float*)d_in[7];
  const float* bv = (const float*)d_in[8];
  float* out = (float*)d_out;

  char* ws = (char*)d_ws;
  short* qsb = (short*)d_out;             // Q bf16 in first 512B of each out row
  short* ksb = (short*)ws;                // 8 MB [b][s][dk] bf16
  short* vtb = (short*)(ws + (8 << 20));  // 8 MB [b][dv][s] bf16

  proj3<<<dim3(2, 128, 3), dim3(256), 0, stream>>>(
      q_in, k_in, v_in, bq, bk, bv, Wq, Wk, Wv, qsb, ksb, vtb);
  attn_fused<<<dim3(256), dim3(512), 0, stream>>>(qsb, ksb, vtb, out);
}

// Round 7
// 120.410 us; speedup vs baseline: 1.2174x; 1.0397x over previous
//
#include <hip/hip_runtime.h>
#include <hip/hip_bf16.h>

// SingleAttention: q/k/v = X@W+b (fp32 in), out = softmax(q k^T/16) v, fp32 out.
// B=8 S=2048 D_IN=512 D_K=D_V=256.
// ws: EXACTLY 16 MB = ks bf16 [8][2048][256] (8MB) + vt bf16 [8][dv=256][s=2048] (8MB).
// Q (bf16, scaled by 1/16) is stashed in the first 512B of each d_out row
// (stride 512 shorts); each attn block reads only its own rows, then
// overwrites them in its epilogue.

typedef __attribute__((ext_vector_type(4))) float f32x4;
typedef __attribute__((ext_vector_type(8))) short s16x8;
typedef __attribute__((ext_vector_type(4))) short s16x4;

static __device__ __forceinline__ short f2bf(float x) {
  __hip_bfloat16 h = __float2bfloat16(x);
  return *reinterpret_cast<short*>(&h);
}
static __device__ __forceinline__ unsigned pack2bf(float lo, float hi) {
  return (unsigned)(unsigned short)f2bf(lo) |
         ((unsigned)(unsigned short)f2bf(hi) << 16);
}

// Projection: P[16384,256] = X @ W + b -> bf16.
// z=0 -> qs (scaled 1/16), row stride 512; z=1 -> ks, stride 256;
// z=2 -> vt transposed [b][dv][s].
__global__ __launch_bounds__(256) void proj3(
    const float* __restrict__ q_in, const float* __restrict__ k_in,
    const float* __restrict__ v_in, const float* __restrict__ bq,
    const float* __restrict__ bk, const float* __restrict__ bv,
    const float* __restrict__ Wq, const float* __restrict__ Wk,
    const float* __restrict__ Wv, short* __restrict__ qs,
    short* __restrict__ ks, short* __restrict__ vt) {
  const int z = blockIdx.z;
  const float* X = z == 0 ? q_in : z == 1 ? k_in : v_in;
  const float* W = z == 0 ? Wq : z == 1 ? Wk : Wv;
  const float* bias = z == 0 ? bq : z == 1 ? bk : bv;
  const float sc = z == 0 ? 0.0625f : 1.0f;
  const int n0 = blockIdx.x * 128;
  const int m0 = blockIdx.y * 128;

  __shared__ short As[128][40];
  __shared__ short Bs[128][40];

  const int tid = threadIdx.x;
  const int lane = tid & 63;
  const int wid = tid >> 6;
  const int wr = wid >> 1, wc = wid & 1;
  const int g = lane >> 4, c = lane & 15;

  f32x4 acc[4][4];
#pragma unroll
  for (int m = 0; m < 4; m++)
#pragma unroll
    for (int n = 0; n < 4; n++) acc[m][n] = (f32x4)0.0f;

  const int arow = tid >> 1, ahalf = tid & 1;
  const int bn = tid & 127, bhalf = tid >> 7;

  for (int kt = 0; kt < 16; ++kt) {
    const int k0 = kt * 32;
    const float* ap = &X[(m0 + arow) * 512 + k0 + ahalf * 16];
    f32x4 a0 = *(const f32x4*)(ap + 0);
    f32x4 a1 = *(const f32x4*)(ap + 4);
    f32x4 a2 = *(const f32x4*)(ap + 8);
    f32x4 a3 = *(const f32x4*)(ap + 12);
    float wv[16];
#pragma unroll
    for (int j = 0; j < 16; j++)
      wv[j] = W[(k0 + bhalf * 16 + j) * 256 + n0 + bn] * sc;
    __syncthreads();
    s16x8 ac0, ac1, w0, w1;
#pragma unroll
    for (int i = 0; i < 4; i++) {
      ac0[i] = f2bf(a0[i]);
      ac0[i + 4] = f2bf(a1[i]);
      ac1[i] = f2bf(a2[i]);
      ac1[i + 4] = f2bf(a3[i]);
    }
#pragma unroll
    for (int j = 0; j < 8; j++) {
      w0[j] = f2bf(wv[j]);
      w1[j] = f2bf(wv[8 + j]);
    }
    *(s16x8*)&As[arow][ahalf * 16 + 0] = ac0;
    *(s16x8*)&As[arow][ahalf * 16 + 8] = ac1;
    *(s16x8*)&Bs[bn][bhalf * 16 + 0] = w0;
    *(s16x8*)&Bs[bn][bhalf * 16 + 8] = w1;
    __syncthreads();
    s16x8 af[4], bfr[4];
#pragma unroll
    for (int m = 0; m < 4; m++)
      af[m] = *(const s16x8*)&As[wr * 64 + m * 16 + c][g * 8];
#pragma unroll
    for (int n = 0; n < 4; n++)
      bfr[n] = *(const s16x8*)&Bs[wc * 64 + n * 16 + c][g * 8];
#pragma unroll
    for (int m = 0; m < 4; m++)
#pragma unroll
      for (int n = 0; n < 4; n++)
        acc[m][n] = __builtin_amdgcn_mfma_f32_16x16x32_bf16(af[m], bfr[n],
                                                            acc[m][n], 0, 0, 0);
  }

  float bv4[4];
#pragma unroll
  for (int n = 0; n < 4; n++) bv4[n] = bias[n0 + wc * 64 + n * 16 + c] * sc;

  if (z <= 1) {
    short* outp = z == 0 ? qs : ks;
    const int ostr = z == 0 ? 512 : 256;
#pragma unroll
    for (int m = 0; m < 4; m++) {
      const int row0 = m0 + wr * 64 + m * 16 + g * 4;
#pragma unroll
      for (int n = 0; n < 4; n++) {
        const int col = n0 + wc * 64 + n * 16 + c;
#pragma unroll
        for (int r = 0; r < 4; r++)
          outp[(row0 + r) * ostr + col] = f2bf(acc[m][n][r] + bv4[n]);
      }
    }
  } else {
#pragma unroll
    for (int m = 0; m < 4; m++) {
      const int row0 = m0 + wr * 64 + m * 16 + g * 4;
      const int bb = row0 >> 11, s = row0 & 2047;
#pragma unroll
      for (int n = 0; n < 4; n++) {
        const int col = n0 + wc * 64 + n * 16 + c;
        s16x4 pk;
#pragma unroll
        for (int r = 0; r < 4; r++) pk[r] = f2bf(acc[m][n][r] + bv4[n]);
        *(s16x4*)&vt[bb * 524288 + col * 2048 + s] = pk;  // vt[b][dv][s]
      }
    }
  }
}

// Flash attention with in-block KV split. Flat grid 256: b = bid&7 (XCD-local
// batch -> K/V L2-resident), q0 = (bid>>3)*64. 512 threads = 8 waves:
// waves 0-3: kv tiles 0..15; waves 4-7: kv tiles 16..31.
// QK^T computed SWAPPED (mfma(K,Q) -> S^T): lane (c,g) holds 16 S-values of
// the single q-row c -> lane-local softmax (2 shfl_xor), per-lane (m,l).
__global__ __launch_bounds__(512, 2) void attn_fused(
    const short* __restrict__ qs, const short* __restrict__ ks,
    const short* __restrict__ vt, float* __restrict__ out) {
  const int bid = blockIdx.x;
  const int b = bid & 7;
  const int q0 = (bid >> 3) * 64;

  // LDS carve (160256 B):
  //   0      KsA[64][264]   33792   (merge: Om overlay)
  //   33792  VsA[256][72]   36864   (merge: Om cont'd)
  //   70656  KsB[64][264]   33792   (merge: Ml overlay)
  //   104448 VsB[256][72]   36864
  //   141312 Ps[8][16][74]  18944   (ends at 160256; stride 74 = 37 dw)
  __shared__ __align__(16) char smem[160256];
  short(*KsA)[264] = (short(*)[264])(smem);
  short(*VsA)[72] = (short(*)[72])(smem + 33792);
  short(*KsB)[264] = (short(*)[264])(smem + 70656);
  short(*VsB)[72] = (short(*)[72])(smem + 104448);
  short(*Ps)[16][74] = (short(*)[16][74])(smem + 141312);
  float(*Om)[260] = (float(*)[260])(smem);        // 64*260*4 = 66560 <= 70656
  float(*Ml)[2] = (float(*)[2])(smem + 70656);

  const int tid = threadIdx.x;
  const int lane = tid & 63;
  const int wid = tid >> 6;    // 0..7
  const int grp = tid >> 8;    // 0/1
  const int gtid = tid & 255;  // within group
  const int wq = wid & 3;      // q-row fragment (16 rows)
  const int g = lane >> 4, c = lane & 15;

  // hoist Q fragments from global (bf16, pre-scaled by 1/16)
  s16x8 qf[8];
  {
    const int qrow = (b << 11) + q0 + wq * 16 + c;
#pragma unroll
    for (int d = 0; d < 8; d++)
      qf[d] = *(const s16x8*)&qs[qrow * 512 + d * 32 + g * 8];
  }

  short(*Ks)[264] = grp ? KsB : KsA;
  short(*Vs)[72] = grp ? VsB : VsA;
  const int ktbase = grp * 16;

  f32x4 o[16];
#pragma unroll
  for (int f = 0; f < 16; f++) o[f] = (f32x4)0.0f;
  float m_l = -1e30f;  // running max of q-row c (this lane's row)
  float l_l = 0.f;     // running sum of q-row c

  // prologue: load first tile into regs
  s16x8 kreg[8], vreg[8];
#pragma unroll
  for (int i = 0; i < 8; i++) {
    const int ch = gtid + i * 256;
    kreg[i] = *(const s16x8*)&ks[((b << 11) + ktbase * 64 + (ch >> 5)) * 256 +
                                 (ch & 31) * 8];
    vreg[i] = *(const s16x8*)&vt[b * 524288 + (ch >> 3) * 2048 + ktbase * 64 +
                                 (ch & 7) * 8];
  }

  for (int t = 0; t < 16; ++t) {
    __syncthreads();  // prev compute's LDS reads done
#pragma unroll
    for (int i = 0; i < 8; i++) {
      const int ch = gtid + i * 256;
      *(s16x8*)&Ks[ch >> 5][(ch & 31) * 8] = kreg[i];
      *(s16x8*)&Vs[ch >> 3][(ch & 7) * 8] = vreg[i];
    }
    __syncthreads();  // tiles ready

    if (t < 15) {  // next-tile loads fly under this tile's compute
      const int kt = ktbase + t + 1;
#pragma unroll
      for (int i = 0; i < 8; i++) {
        const int ch = gtid + i * 256;
        kreg[i] = *(const s16x8*)&ks[((b << 11) + kt * 64 + (ch >> 5)) * 256 +
                                     (ch & 31) * 8];
        vreg[i] = *(const s16x8*)&vt[b * 524288 + (ch >> 3) * 2048 + kt * 64 +
                                     (ch & 7) * 8];
      }
    }

    // S^T = K Q^T (swapped): sf[nf][r] = S[q=c][kv = nf*16 + g*4 + r]
    f32x4 sf[4];
#pragma unroll
    for (int nf = 0; nf < 4; nf++) sf[nf] = (f32x4)0.0f;
    __builtin_amdgcn_s_setprio(1);
#pragma unroll
    for (int d = 0; d < 8; d++) {
#pragma unroll
      for (int nf = 0; nf < 4; nf++) {
        const s16x8 kf = *(const s16x8*)&Ks[nf * 16 + c][d * 32 + g * 8];
        sf[nf] = __builtin_amdgcn_mfma_f32_16x16x32_bf16(kf, qf[d], sf[nf], 0, 0, 0);
      }
    }
    __builtin_amdgcn_s_setprio(0);

    // lane-local online softmax with defer-max (THR=8); row = c, spread over 4 g
    float mx = sf[0][0];
#pragma unroll
    for (int nf = 0; nf < 4; nf++)
#pragma unroll
      for (int r = 0; r < 4; r++) mx = fmaxf(mx, sf[nf][r]);
    mx = fmaxf(mx, __shfl_xor(mx, 16, 64));
    mx = fmaxf(mx, __shfl_xor(mx, 32, 64));
    if (__any(mx > m_l + 8.f)) {  // wave-uniform rescale
      const float mn = fmaxf(m_l, mx);
      const float scr = __expf(m_l - mn);
      m_l = mn;
      l_l *= scr;
      float so[4];
#pragma unroll
      for (int r = 0; r < 4; r++) so[r] = __shfl(scr, g * 4 + r, 64);
#pragma unroll
      for (int f = 0; f < 16; f++)
#pragma unroll
        for (int r = 0; r < 4; r++) o[f][r] *= so[r];
    }
    float sum = 0.f;
#pragma unroll
    for (int nf = 0; nf < 4; nf++)
#pragma unroll
      for (int r = 0; r < 4; r++) {
        const float p = __expf(sf[nf][r] - m_l);
        sf[nf][r] = p;
        sum += p;
      }
    sum += __shfl_xor(sum, 16, 64);
    sum += __shfl_xor(sum, 32, 64);
    l_l += sum;

    // P -> wave-private LDS, packed bf16x2 (no barrier: same-wave ds ordering)
#pragma unroll
    for (int nf = 0; nf < 4; nf++)
#pragma unroll
      for (int i = 0; i < 2; i++)
        *(unsigned*)&Ps[wid][c][nf * 16 + g * 4 + 2 * i] =
            pack2bf(sf[nf][2 * i], sf[nf][2 * i + 1]);

    // O += P V
    __builtin_amdgcn_s_setprio(1);
#pragma unroll
    for (int k2 = 0; k2 < 2; k2++) {
      const s16x8 pa = *(const s16x8*)&Ps[wid][c][k2 * 32 + g * 8];
#pragma unroll
      for (int f = 0; f < 16; f++) {
        const s16x8 vf = *(const s16x8*)&Vs[f * 16 + c][k2 * 32 + g * 8];
        o[f] = __builtin_amdgcn_mfma_f32_16x16x32_bf16(pa, vf, o[f], 0, 0, 0);
      }
    }
    __builtin_amdgcn_s_setprio(0);
  }

  // transport per-row (m,l) to O-fragment lanes: row g*4+r lives on lane g*4+r
  float m0r[4], l0r[4];
#pragma unroll
  for (int r = 0; r < 4; r++) {
    m0r[r] = __shfl(m_l, g * 4 + r, 64);
    l0r[r] = __shfl(l_l, g * 4 + r, 64);
  }

  // ---- merge the two KV-half states and write out ----
  __syncthreads();  // all compute done; LDS free
  if (grp == 1) {
#pragma unroll
    for (int f = 0; f < 16; f++)
#pragma unroll
      for (int r = 0; r < 4; r++)
        Om[wq * 16 + g * 4 + r][f * 16 + c] = o[f][r];
    if (g == 0) {
      Ml[wq * 16 + c][0] = m_l;
      Ml[wq * 16 + c][1] = l_l;
    }
  }
  __syncthreads();
  if (grp == 0) {
    float e0v[4], e1v[4], inv[4];
#pragma unroll
    for (int r = 0; r < 4; r++) {
      const int rw = wq * 16 + g * 4 + r;
      const float m1 = Ml[rw][0], l1 = Ml[rw][1];
      const float ms = fmaxf(m0r[r], m1);
      e0v[r] = __expf(m0r[r] - ms);
      e1v[r] = __expf(m1 - ms);
      inv[r] = 1.0f / (l0r[r] * e0v[r] + l1 * e1v[r]);
    }
#pragma unroll
    for (int f = 0; f < 16; f++) {
#pragma unroll
      for (int r = 0; r < 4; r++) {
        const int rw = wq * 16 + g * 4 + r;
        const int col = f * 16 + c;
        out[((b << 11) + q0 + rw) * 256 + col] =
            (o[f][r] * e0v[r] + Om[rw][col] * e1v[r]) * inv[r];
      }
    }
  }
}

extern "C" void kernel_launch(void* const* d_in, const int* in_sizes, int n_in,
                              void* d_out, int out_size, void* d_ws,
                              size_t ws_size, hipStream_t stream) {
  const float* q_in = (const float*)d_in[0];
  const float* k_in = (const float*)d_in[1];
  const float* v_in = (const float*)d_in[2];
  const float* Wq = (const float*)d_in[3];
  const float* bq = (const float*)d_in[4];
  const float* Wk = (const float*)d_in[5];
  const float* bk = (const float*)d_in[6];
  const float* Wv = (const float*)d_in[7];
  const float* bv = (const float*)d_in[8];
  float* out = (float*)d_out;

  char* ws = (char*)d_ws;
  short* qsb = (short*)d_out;             // Q bf16 in first 512B of each out row
  short* ksb = (short*)ws;                // 8 MB [b][s][dk] bf16
  short* vtb = (short*)(ws + (8 << 20));  // 8 MB [b][dv][s] bf16

  proj3<<<dim3(2, 128, 3), dim3(256), 0, stream>>>(
      q_in, k_in, v_in, bq, bk, bv, Wq, Wk, Wv, qsb, ksb, vtb);
  attn_fused<<<dim3(256), dim3(512), 0, stream>>>(qsb, ksb, vtb, out);
}